// Round 9
// baseline (26.257 us; speedup 1.0000x reference)
//
#include <hip/hip_runtime.h>
#include <hip/hip_bf16.h>

// Additive attention weights: B=2,H=4,LQ=LKV=512,D=64, fp32 in/out.
//   tanh(x) = 1 - 2/(1+e^{2x});  softmax drops uniform shift (sum w + b_logit)
//   => logit ~ sum_e w'_e/(1+e^{2x_e}),  w' = -2w,  x = qp+kp+b
//   e^{2x} = EQ*EK,  EQ=2^{(qp+b)*2log2e}, EK=2^{kp*2log2e}  (precomputed)
// 4-way rational combine over e (1 rcp per 4 e-terms). EK TRANSPOSED
// [bh][e][k]. attn R9: thread rectangle = 4 q-rows x 2 k (acc still 8
// floats, K-regs halve), block = 4 rows x full 512 k -> slab read ONCE
// per block: L2 traffic 268->134 MB. No launch_bounds waves-arg (R6/R7:
// it forced a 64-VGPR clamp + scratch spill).

#define NQROWS 4096   // B*H*LQ

// ---------------- kernel A: projections + exp2 ----------------
// 8 rows/block: blocks [0,512) Q rows, [512,1024) K rows. 4 waves/block.
__global__ __launch_bounds__(256) void proj_kernel(
    const float* __restrict__ Q, const float* __restrict__ K,
    const float* __restrict__ W, const float* __restrict__ bC,
    float* __restrict__ eq, float* __restrict__ ekt)
{
  const int t  = threadIdx.x;
  const int tr = t >> 6;        // 0..3
  const int e  = t & 63;
  const int rbase = blockIdx.x * 8;
  const bool isK = rbase >= NQROWS;
  const int r0 = isK ? rbase - NQROWS : rbase;
  const float* __restrict__ src = isK ? K : Q;
  const int off = isK ? 64 : 0;

  __shared__ float  srow[8][64];     // 2KB
  __shared__ float4 wsh[64][16];     // 16KB, XOR-swizzled (f4 col ^ (row&7))
  __shared__ float  trsp[64][9];     // 2.3KB, K-store transpose (pad 9)

  for (int i = t; i < 8 * 64; i += 256)
    srow[i >> 6][i & 63] = src[(r0 + (i >> 6)) * 64 + (i & 63)];
  for (int i = t; i < 64 * 16; i += 256) {
    const int er = i >> 4, d4 = i & 15;
    wsh[er][d4 ^ (er & 7)] =
        reinterpret_cast<const float4*>(W + er * 128 + off)[d4];
  }
  __syncthreads();

  float acc0 = 0.f, acc1 = 0.f;
  const int rA = tr * 2;
  #pragma unroll
  for (int d4 = 0; d4 < 16; ++d4) {
    const float4 w4 = wsh[e][d4 ^ (e & 7)];
    const float4 s0 = *reinterpret_cast<const float4*>(&srow[rA + 0][d4 * 4]);
    const float4 s1 = *reinterpret_cast<const float4*>(&srow[rA + 1][d4 * 4]);
    acc0 = fmaf(s0.x, w4.x, acc0); acc0 = fmaf(s0.y, w4.y, acc0);
    acc0 = fmaf(s0.z, w4.z, acc0); acc0 = fmaf(s0.w, w4.w, acc0);
    acc1 = fmaf(s1.x, w4.x, acc1); acc1 = fmaf(s1.y, w4.y, acc1);
    acc1 = fmaf(s1.z, w4.z, acc1); acc1 = fmaf(s1.w, w4.w, acc1);
  }

  const float C2 = 2.8853900817779268f;   // 2*log2(e)
  if (!isK) {
    const float bias = bC[e];
    eq[(r0 + rA + 0) * 64 + e] = __builtin_amdgcn_exp2f((acc0 + bias) * C2);
    eq[(r0 + rA + 1) * 64 + e] = __builtin_amdgcn_exp2f((acc1 + bias) * C2);
  } else {
    // transpose in LDS, then coalesced store to ekt[bh][e][k0..k0+7]
    trsp[e][rA + 0] = __builtin_amdgcn_exp2f(acc0 * C2);
    trsp[e][rA + 1] = __builtin_amdgcn_exp2f(acc1 * C2);
    __syncthreads();                       // block-uniform branch: legal
    const int bh = r0 >> 9;
    const int k0 = r0 & 511;
    float* __restrict__ dst = ekt + bh * 64 * 512 + k0;
    #pragma unroll
    for (int iter = 0; iter < 2; ++iter) {
      const int i  = t + iter * 256;
      const int e2 = i >> 3, kk = i & 7;
      dst[e2 * 512 + kk] = trsp[e2][kk];
    }
  }
}

// ---------------- kernel B: fused logits + masked softmax ----------------
// Grid: 1024 blocks; bh = blk&7 (XCD-affine), qg = blk>>3; 4 q-rows/block.
// 256 threads: thread c = t owns k-pair {2c, 2c+1} for ALL 4 rows
// (4 rows x 2 k x 64 e = 512 evals/thread; one float2 EK load feeds 8
// evals; block reads the 128KB slab exactly once). Row spans 4 waves ->
// shfl reduce + 4-wave LDS combine. No-max softmax (|logit| <= ~2).
__global__ __launch_bounds__(256) void attn_kernel(
    const float* __restrict__ eq, const float* __restrict__ ekt,
    const float* __restrict__ wl, const int* __restrict__ mask,
    float* __restrict__ out)
{
  const int t  = threadIdx.x;
  const int c  = t;             // k float2-column (k = 2c)
  const int wv = t >> 6;        // wave 0..3
  const int ln = t & 63;
  const int bh = blockIdx.x & 7;
  const int qg = blockIdx.x >> 3;   // 0..127
  const int b  = bh >> 2;       // H=4
  const int q0 = qg * 4;

  __shared__ float qsh[4][64];
  __shared__ float w2s[64];
  __shared__ float s_sm[4][4], s_sr[4][4];
  __shared__ int   s_any[4][4];

  if (t < 64) w2s[t] = -2.0f * wl[t];
  qsh[t >> 6][t & 63] = eq[(bh * 512 + q0 + (t >> 6)) * 64 + (t & 63)];
  __syncthreads();

  const float2* __restrict__ kq =
      reinterpret_cast<const float2*>(ekt + bh * 64 * 512) + c;

  float2 a0 = {0.f, 0.f}, a1 = {0.f, 0.f}, a2 = {0.f, 0.f}, a3 = {0.f, 0.f};

  // one k-component (CMP) of 4 e-terms for one q-row: 12 VALU + 1 rcp
#define QK(AC, QV, CMP)                                                       \
  {                                                                           \
    const float t0 = fmaf(QV.x, Ka.CMP, 1.f);                                 \
    const float t1 = fmaf(QV.y, Kb.CMP, 1.f);                                 \
    const float t2 = fmaf(QV.z, Kc.CMP, 1.f);                                 \
    const float t3 = fmaf(QV.w, Kd.CMP, 1.f);                                 \
    const float t01 = t0 * t1, t23 = t2 * t3;                                 \
    const float den = t01 * t23;                                              \
    const float n01 = fmaf(w4.x, t1, w4.y * t0);                              \
    const float n23 = fmaf(w4.z, t3, w4.w * t2);                              \
    const float num = fmaf(n01, t23, n23 * t01);                              \
    AC.CMP = fmaf(num, __builtin_amdgcn_rcpf(den), AC.CMP);                   \
  }

  #pragma unroll 4
  for (int eb = 0; eb < 16; ++eb) {
    const float2 Ka = kq[(eb * 4 + 0) * 256];
    const float2 Kb = kq[(eb * 4 + 1) * 256];
    const float2 Kc = kq[(eb * 4 + 2) * 256];
    const float2 Kd = kq[(eb * 4 + 3) * 256];
    const float4 qa = *reinterpret_cast<const float4*>(&qsh[0][eb * 4]);
    const float4 qb = *reinterpret_cast<const float4*>(&qsh[1][eb * 4]);
    const float4 qc = *reinterpret_cast<const float4*>(&qsh[2][eb * 4]);
    const float4 qd = *reinterpret_cast<const float4*>(&qsh[3][eb * 4]);
    const float4 w4 = *reinterpret_cast<const float4*>(&w2s[eb * 4]);
    QK(a0, qa, x) QK(a0, qa, y)
    QK(a1, qb, x) QK(a1, qb, y)
    QK(a2, qc, x) QK(a2, qc, y)
    QK(a3, qd, x) QK(a3, qd, y)
  }

  // ---- mask (loaded after main loop; not held across it) ----
  const int* __restrict__ mb = mask + (b * 512 + q0) * 512 + 2 * c;
  const int2 mv0 = *reinterpret_cast<const int2*>(mb);
  const int2 mv1 = *reinterpret_cast<const int2*>(mb + 512);
  const int2 mv2 = *reinterpret_cast<const int2*>(mb + 1024);
  const int2 mv3 = *reinterpret_cast<const int2*>(mb + 1536);

  // ---- no-max softmax: |logit| <= sum|2w| (~2) -> exp2 safe ----
  const float L2E = 1.4426950408889634f;
  float2 p0, p1, p2, p3;
  p0.x = __builtin_amdgcn_exp2f(a0.x * L2E);
  p0.y = __builtin_amdgcn_exp2f(a0.y * L2E);
  p1.x = __builtin_amdgcn_exp2f(a1.x * L2E);
  p1.y = __builtin_amdgcn_exp2f(a1.y * L2E);
  p2.x = __builtin_amdgcn_exp2f(a2.x * L2E);
  p2.y = __builtin_amdgcn_exp2f(a2.y * L2E);
  p3.x = __builtin_amdgcn_exp2f(a3.x * L2E);
  p3.y = __builtin_amdgcn_exp2f(a3.y * L2E);

  float sm0 = (mv0.x ? p0.x : 0.f) + (mv0.y ? p0.y : 0.f);
  float sm1 = (mv1.x ? p1.x : 0.f) + (mv1.y ? p1.y : 0.f);
  float sm2 = (mv2.x ? p2.x : 0.f) + (mv2.y ? p2.y : 0.f);
  float sm3 = (mv3.x ? p3.x : 0.f) + (mv3.y ? p3.y : 0.f);
  float sr0 = p0.x + p0.y;
  float sr1 = p1.x + p1.y;
  float sr2 = p2.x + p2.y;
  float sr3 = p3.x + p3.y;
  const int any0 = __any((mv0.x | mv0.y) != 0) ? 1 : 0;
  const int any1 = __any((mv1.x | mv1.y) != 0) ? 1 : 0;
  const int any2 = __any((mv2.x | mv2.y) != 0) ? 1 : 0;
  const int any3 = __any((mv3.x | mv3.y) != 0) ? 1 : 0;

  #pragma unroll
  for (int s = 1; s < 64; s <<= 1) {
    sm0 += __shfl_xor(sm0, s); sm1 += __shfl_xor(sm1, s);
    sm2 += __shfl_xor(sm2, s); sm3 += __shfl_xor(sm3, s);
    sr0 += __shfl_xor(sr0, s); sr1 += __shfl_xor(sr1, s);
    sr2 += __shfl_xor(sr2, s); sr3 += __shfl_xor(sr3, s);
  }
  if (ln == 0) {
    s_sm[wv][0] = sm0; s_sm[wv][1] = sm1; s_sm[wv][2] = sm2; s_sm[wv][3] = sm3;
    s_sr[wv][0] = sr0; s_sr[wv][1] = sr1; s_sr[wv][2] = sr2; s_sr[wv][3] = sr3;
    s_any[wv][0] = any0; s_any[wv][1] = any1;
    s_any[wv][2] = any2; s_any[wv][3] = any3;
  }
  __syncthreads();

#define ROWOUT(P, MV, I)                                                      \
  {                                                                           \
    const bool ra =                                                           \
        (s_any[0][I] | s_any[1][I] | s_any[2][I] | s_any[3][I]) != 0;         \
    const float sm =                                                          \
        (s_sm[0][I] + s_sm[1][I]) + (s_sm[2][I] + s_sm[3][I]);                \
    const float sr =                                                          \
        (s_sr[0][I] + s_sr[1][I]) + (s_sr[2][I] + s_sr[3][I]);                \
    const float inv = 1.0f / (ra ? sm : sr);                                  \
    float2 o2;                                                                \
    o2.x = ((!ra || MV.x) ? P.x : 0.f) * inv;                                 \
    o2.y = ((!ra || MV.y) ? P.y : 0.f) * inv;                                 \
    *reinterpret_cast<float2*>(                                               \
        out + (bh * 512 + q0 + (I)) * 512 + 2 * c) = o2;                      \
  }
  ROWOUT(p0, mv0, 0)
  ROWOUT(p1, mv1, 1)
  ROWOUT(p2, mv2, 2)
  ROWOUT(p3, mv3, 3)
}

extern "C" void kernel_launch(void* const* d_in, const int* in_sizes, int n_in,
                              void* d_out, int out_size, void* d_ws, size_t ws_size,
                              hipStream_t stream) {
  const float* Q  = (const float*)d_in[0];
  const float* K  = (const float*)d_in[1];
  // d_in[2] = values : unused by the reference output
  const int*   M  = (const int*)d_in[3];
  const float* W  = (const float*)d_in[4];
  const float* bC = (const float*)d_in[5];
  const float* wl = (const float*)d_in[6];
  // d_in[7] = b_logit : uniform shift, cancels in softmax
  float* out = (float*)d_out;
  float* eqbuf  = (float*)d_ws;            // 4096*64 floats = 1MB
  float* ektbuf = eqbuf + NQROWS * 64;     // 8*64*512 floats = 1MB, transposed

  proj_kernel<<<1024, 256, 0, stream>>>(Q, K, W, bC, eqbuf, ektbuf);
  attn_kernel<<<1024, 256, 0, stream>>>(eqbuf, ektbuf, wl, M, out);
}